// Round 1
// baseline (999.134 us; speedup 1.0000x reference)
//
#include <hip/hip_runtime.h>
#include <math.h>

#define NN 50000
#define NE 600000
#define HID 128
#define NCLS 10

typedef __bf16 bf16x8 __attribute__((ext_vector_type(8)));
typedef float f32x16 __attribute__((ext_vector_type(16)));

// Exact 3-way bf16 split: f == hi + mid + lo (bit-truncation splits are exact;
// fp32 has 24 mantissa bits, 3x bf16 planes carry 8+8+8 = all of them).
__device__ __forceinline__ void split3(float f, ushort& h, ushort& m, ushort& l) {
    unsigned uh = __float_as_uint(f) & 0xffff0000u;
    float fm = f - __uint_as_float(uh);
    unsigned um = __float_as_uint(fm) & 0xffff0000u;
    float fl = fm - __uint_as_float(um);
    h = (ushort)(uh >> 16);
    m = (ushort)(um >> 16);
    l = (ushort)(__float_as_uint(fl) >> 16);
}

// ================= graph prep: CSR by destination =================

__global__ __launch_bounds__(256) void k_count(const int* __restrict__ edge,
                                               int* __restrict__ counts) {
    int e = blockIdx.x * 256 + threadIdx.x;
    if (e < NE) atomicAdd(&counts[edge[NE + e]], 1);
}

__device__ __forceinline__ int wave_incl_scan(int x, int lane) {
#pragma unroll
    for (int off = 1; off < 64; off <<= 1) {
        int y = __shfl_up(x, off, 64);
        if (lane >= off) x += y;
    }
    return x;
}

__global__ __launch_bounds__(256) void k_scan1(const int* __restrict__ counts,
                                               int* __restrict__ rowptr,
                                               int* __restrict__ bsum,
                                               float* __restrict__ dinv) {
    __shared__ int ws[4];
    int tid = threadIdx.x;
    int i = blockIdx.x * 256 + tid;
    int lane = tid & 63, wv = tid >> 6;
    int v = (i < NN) ? counts[i] : 0;
    if (i < NN) dinv[i] = rsqrtf((float)(v + 1));
    int x = wave_incl_scan(v, lane);
    if (lane == 63) ws[wv] = x;
    __syncthreads();
    int off = 0;
    for (int j = 0; j < wv; ++j) off += ws[j];
    if (i < NN) rowptr[i] = off + x - v;
    if (tid == 255) bsum[blockIdx.x] = off + x;
}

__global__ __launch_bounds__(256) void k_scan2(int* __restrict__ bsum, int n) {
    __shared__ int ws[4];
    int tid = threadIdx.x;
    int lane = tid & 63, wv = tid >> 6;
    int v = (tid < n) ? bsum[tid] : 0;
    int x = wave_incl_scan(v, lane);
    if (lane == 63) ws[wv] = x;
    __syncthreads();
    int off = 0;
    for (int j = 0; j < wv; ++j) off += ws[j];
    __syncthreads();
    if (tid < n) bsum[tid] = off + x - v;
}

__global__ __launch_bounds__(256) void k_scan3(int* __restrict__ rowptr,
                                               const int* __restrict__ bsum) {
    int i = blockIdx.x * 256 + threadIdx.x;
    if (i < NN) rowptr[i] += bsum[blockIdx.x];
    if (i == 0) rowptr[NN] = NE;
}

__global__ __launch_bounds__(256) void k_fill(const int* __restrict__ edge,
                                              const int* __restrict__ rowptr,
                                              int* __restrict__ cursor,
                                              const float* __restrict__ dinv,
                                              int2* __restrict__ csr) {
    int e = blockIdx.x * 256 + threadIdx.x;
    if (e >= NE) return;
    int s = edge[e], d = edge[NE + e];
    int p = rowptr[d] + atomicAdd(&cursor[d], 1);
    csr[p] = make_int2(s, __float_as_int(dinv[s] * dinv[d]));
}

// ================= one-time splits =================

// W_stack [8][128 k][128 n] fp32 -> Wt3 [8][3 planes][128 n][128 k] bf16 (transposed)
__global__ __launch_bounds__(256) void k_split_w(const float* __restrict__ Wst,
                                                 ushort* __restrict__ Wt3) {
    int i = blockIdx.x * 256 + threadIdx.x;
    if (i >= 8 * HID * HID) return;
    int l = i >> 14;
    int k = (i >> 7) & 127;
    int n = i & 127;
    ushort h, m, lo;
    split3(Wst[i], h, m, lo);
    size_t base = (size_t)l * 3 * HID * HID + (size_t)n * HID + k;
    Wt3[base] = h;
    Wt3[base + HID * HID] = m;
    Wt3[base + 2 * HID * HID] = lo;
}

// x [NN][128] fp32 -> 3 bf16 planes
__global__ __launch_bounds__(256) void k_split_x(const float* __restrict__ x,
                                                 ushort* __restrict__ Ah,
                                                 ushort* __restrict__ Am,
                                                 ushort* __restrict__ Al) {
    int i = blockIdx.x * 256 + threadIdx.x;
    if (i >= NN * HID / 8) return;
    const float4* src = (const float4*)x + (size_t)i * 2;
    float4 a = src[0], b = src[1];
    float vals[8] = {a.x, a.y, a.z, a.w, b.x, b.y, b.z, b.w};
    union { ushort u[8]; uint4 v; } ph, pm, pl;
#pragma unroll
    for (int q = 0; q < 8; ++q) split3(vals[q], ph.u[q], pm.u[q], pl.u[q]);
    ((uint4*)Ah)[i] = ph.v;
    ((uint4*)Am)[i] = pm.v;
    ((uint4*)Al)[i] = pl.v;
}

// ========== dense: planes(H) [NN,128] @ W[128,128] -> T fp32, via bf16 MFMA ==========
// Tile 64 rows x 128 cols, 4 waves (wy = row-half of 32, wx = col-half of 64).
// 6 plane-products (hh, hm, mh, hl, mm, lh) == fp32-accurate GEMM.
// LDS rows stride 40 bf16 (odd 16B-granule) -> conflict-free ds_read_b128.

__global__ __launch_bounds__(256) void k_mfma_gemm(const ushort* __restrict__ Ah,
                                                   const ushort* __restrict__ Am,
                                                   const ushort* __restrict__ Al,
                                                   const ushort* __restrict__ Wt,
                                                   float* __restrict__ T) {
    __shared__ ushort As[3][64][40];   // [plane][row][k-slice 32 + pad]
    __shared__ ushort Bs[3][128][40];  // [plane][col][k-slice 32 + pad]
    int tid = threadIdx.x;
    int lane = tid & 63, w = tid >> 6;
    int wy = w >> 1, wx = w & 1;
    int l31 = lane & 31, lh = lane >> 5;
    int rowbase = blockIdx.x * 64;

    int sr = tid >> 2;   // 0..63: A row / B col-half index
    int skq = tid & 3;   // 16B chunk within the 64B k-slice

    int garow = rowbase + sr;
    if (garow >= NN) garow = NN - 1;  // clamp; stores predicated below
    size_t aoff = (size_t)garow * HID;

    f32x16 acc0 = {}, acc1 = {};

    for (int k0 = 0; k0 < HID; k0 += 32) {
        uint4 ra0 = *(const uint4*)(Ah + aoff + k0 + skq * 8);
        uint4 ra1 = *(const uint4*)(Am + aoff + k0 + skq * 8);
        uint4 ra2 = *(const uint4*)(Al + aoff + k0 + skq * 8);
        uint4 rb[6];
#pragma unroll
        for (int i = 0; i < 6; ++i) {
            int p = i >> 1;
            int n = (i & 1) * 64 + sr;
            rb[i] = *(const uint4*)(Wt + p * (HID * HID) + n * HID + k0 + skq * 8);
        }
        __syncthreads();  // previous iter's LDS reads done
        *(uint4*)&As[0][sr][skq * 8] = ra0;
        *(uint4*)&As[1][sr][skq * 8] = ra1;
        *(uint4*)&As[2][sr][skq * 8] = ra2;
#pragma unroll
        for (int i = 0; i < 6; ++i) {
            int p = i >> 1;
            int n = (i & 1) * 64 + sr;
            *(uint4*)&Bs[p][n][skq * 8] = rb[i];
        }
        __syncthreads();
#pragma unroll
        for (int ks = 0; ks < 32; ks += 16) {
            int kk = ks + lh * 8;
            bf16x8 a0 = *(const bf16x8*)&As[0][wy * 32 + l31][kk];
            bf16x8 a1 = *(const bf16x8*)&As[1][wy * 32 + l31][kk];
            bf16x8 a2 = *(const bf16x8*)&As[2][wy * 32 + l31][kk];
            bf16x8 b0n0 = *(const bf16x8*)&Bs[0][wx * 64 + l31][kk];
            bf16x8 b0n1 = *(const bf16x8*)&Bs[0][wx * 64 + 32 + l31][kk];
            bf16x8 b1n0 = *(const bf16x8*)&Bs[1][wx * 64 + l31][kk];
            bf16x8 b1n1 = *(const bf16x8*)&Bs[1][wx * 64 + 32 + l31][kk];
            bf16x8 b2n0 = *(const bf16x8*)&Bs[2][wx * 64 + l31][kk];
            bf16x8 b2n1 = *(const bf16x8*)&Bs[2][wx * 64 + 32 + l31][kk];
            acc0 = __builtin_amdgcn_mfma_f32_32x32x16_bf16(a0, b0n0, acc0, 0, 0, 0);
            acc1 = __builtin_amdgcn_mfma_f32_32x32x16_bf16(a0, b0n1, acc1, 0, 0, 0);
            acc0 = __builtin_amdgcn_mfma_f32_32x32x16_bf16(a1, b0n0, acc0, 0, 0, 0);
            acc1 = __builtin_amdgcn_mfma_f32_32x32x16_bf16(a1, b0n1, acc1, 0, 0, 0);
            acc0 = __builtin_amdgcn_mfma_f32_32x32x16_bf16(a0, b1n0, acc0, 0, 0, 0);
            acc1 = __builtin_amdgcn_mfma_f32_32x32x16_bf16(a0, b1n1, acc1, 0, 0, 0);
            acc0 = __builtin_amdgcn_mfma_f32_32x32x16_bf16(a2, b0n0, acc0, 0, 0, 0);
            acc1 = __builtin_amdgcn_mfma_f32_32x32x16_bf16(a2, b0n1, acc1, 0, 0, 0);
            acc0 = __builtin_amdgcn_mfma_f32_32x32x16_bf16(a1, b1n0, acc0, 0, 0, 0);
            acc1 = __builtin_amdgcn_mfma_f32_32x32x16_bf16(a1, b1n1, acc1, 0, 0, 0);
            acc0 = __builtin_amdgcn_mfma_f32_32x32x16_bf16(a0, b2n0, acc0, 0, 0, 0);
            acc1 = __builtin_amdgcn_mfma_f32_32x32x16_bf16(a0, b2n1, acc1, 0, 0, 0);
        }
    }
    // C/D layout (m74/m101): col = lane&31, row = (reg&3) + 8*(reg>>2) + 4*(lane>>5)
#pragma unroll
    for (int reg = 0; reg < 16; ++reg) {
        int r = (reg & 3) + 8 * (reg >> 2) + 4 * lh;
        int gr = rowbase + wy * 32 + r;
        if (gr < NN) {
            T[(size_t)gr * HID + wx * 64 + l31] = acc0[reg];
            T[(size_t)gr * HID + wx * 64 + 32 + l31] = acc1[reg];
        }
    }
}

// ============ sparse by gather: one wave per node, pipelined, fused epilogue ============
// Output written directly as 3 bf16 planes (next layer's MFMA A-operand).

__global__ __launch_bounds__(256) void k_gather_agg(const float* __restrict__ T,
                                                    ushort* __restrict__ Ah,
                                                    ushort* __restrict__ Am,
                                                    ushort* __restrict__ Al,
                                                    const int* __restrict__ rowptr,
                                                    const int2* __restrict__ csr,
                                                    const float* __restrict__ dinv,
                                                    const float* __restrict__ bias) {
    int lane = threadIdx.x & 63;
    int node = (blockIdx.x * 256 + threadIdx.x) >> 6;
    if (node >= NN) return;
    int slot = lane >> 4, c16 = lane & 15;

    int beg = rowptr[node], end = rowptr[node + 1];
    float4 acc0 = {0.f, 0.f, 0.f, 0.f}, acc1 = {0.f, 0.f, 0.f, 0.f};
    const int2 zed = make_int2(0, 0);  // norm bits 0 -> weight 0

    int i = beg + slot;
    int2 e0 = (i < end) ? csr[i] : zed;
    int2 e1 = (i + 4 < end) ? csr[i + 4] : zed;
    for (; i < end; i += 8) {
        int2 p0 = (i + 8 < end) ? csr[i + 8] : zed;
        int2 p1 = (i + 12 < end) ? csr[i + 12] : zed;
        const float4* s0 = (const float4*)(T + (size_t)e0.x * HID) + c16 * 2;
        const float4* s1 = (const float4*)(T + (size_t)e1.x * HID) + c16 * 2;
        float4 u0 = s0[0], u1 = s0[1];
        float4 v0 = s1[0], v1 = s1[1];
        float w0 = __int_as_float(e0.y);
        float w1 = __int_as_float(e1.y);
        acc0.x += w0 * u0.x; acc0.y += w0 * u0.y; acc0.z += w0 * u0.z; acc0.w += w0 * u0.w;
        acc1.x += w0 * u1.x; acc1.y += w0 * u1.y; acc1.z += w0 * u1.z; acc1.w += w0 * u1.w;
        acc0.x += w1 * v0.x; acc0.y += w1 * v0.y; acc0.z += w1 * v0.z; acc0.w += w1 * v0.w;
        acc1.x += w1 * v1.x; acc1.y += w1 * v1.y; acc1.z += w1 * v1.z; acc1.w += w1 * v1.w;
        e0 = p0; e1 = p1;
    }
    acc0.x += __shfl_xor(acc0.x, 16, 64); acc0.y += __shfl_xor(acc0.y, 16, 64);
    acc0.z += __shfl_xor(acc0.z, 16, 64); acc0.w += __shfl_xor(acc0.w, 16, 64);
    acc1.x += __shfl_xor(acc1.x, 16, 64); acc1.y += __shfl_xor(acc1.y, 16, 64);
    acc1.z += __shfl_xor(acc1.z, 16, 64); acc1.w += __shfl_xor(acc1.w, 16, 64);
    acc0.x += __shfl_xor(acc0.x, 32, 64); acc0.y += __shfl_xor(acc0.y, 32, 64);
    acc0.z += __shfl_xor(acc0.z, 32, 64); acc0.w += __shfl_xor(acc0.w, 32, 64);
    acc1.x += __shfl_xor(acc1.x, 32, 64); acc1.y += __shfl_xor(acc1.y, 32, 64);
    acc1.z += __shfl_xor(acc1.z, 32, 64); acc1.w += __shfl_xor(acc1.w, 32, 64);

    if (slot == 0) {
        float sn = dinv[node];
        sn *= sn;
        const float4* trow = (const float4*)(T + (size_t)node * HID) + c16 * 2;
        float4 t0 = trow[0], t1 = trow[1];
        const float4* b4 = (const float4*)bias + c16 * 2;
        float4 b0 = b4[0], b1 = b4[1];
        float4 r0, r1;
        r0.x = acc0.x + sn * t0.x + b0.x; r0.y = acc0.y + sn * t0.y + b0.y;
        r0.z = acc0.z + sn * t0.z + b0.z; r0.w = acc0.w + sn * t0.w + b0.w;
        r1.x = acc1.x + sn * t1.x + b1.x; r1.y = acc1.y + sn * t1.y + b1.y;
        r1.z = acc1.z + sn * t1.z + b1.z; r1.w = acc1.w + sn * t1.w + b1.w;
        r0.x = r0.x > 0.f ? r0.x : expm1f(r0.x);
        r0.y = r0.y > 0.f ? r0.y : expm1f(r0.y);
        r0.z = r0.z > 0.f ? r0.z : expm1f(r0.z);
        r0.w = r0.w > 0.f ? r0.w : expm1f(r0.w);
        r1.x = r1.x > 0.f ? r1.x : expm1f(r1.x);
        r1.y = r1.y > 0.f ? r1.y : expm1f(r1.y);
        r1.z = r1.z > 0.f ? r1.z : expm1f(r1.z);
        r1.w = r1.w > 0.f ? r1.w : expm1f(r1.w);
        float vals[8] = {r0.x, r0.y, r0.z, r0.w, r1.x, r1.y, r1.z, r1.w};
        union { ushort u[8]; uint4 v; } ph, pm, pl;
#pragma unroll
        for (int q = 0; q < 8; ++q) split3(vals[q], ph.u[q], pm.u[q], pl.u[q]);
        size_t off = (size_t)node * HID + c16 * 8;
        *(uint4*)(Ah + off) = ph.v;
        *(uint4*)(Am + off) = pm.v;
        *(uint4*)(Al + off) = pl.v;
    }
}

// ================= output layer (128 -> 10) =================
// Reads bf16 planes, reconstructs fp32 exactly (hi+mid+lo).

__global__ __launch_bounds__(256) void k_matmul_out(const ushort* __restrict__ Ah,
                                                    const ushort* __restrict__ Am,
                                                    const ushort* __restrict__ Al,
                                                    const float* __restrict__ W,
                                                    float* __restrict__ T2) {
    __shared__ float Ws[128 * 11];
    int tid = threadIdx.x;
    for (int m = tid; m < HID * NCLS; m += 256) {
        int k = m / NCLS, c = m - k * NCLS;
        Ws[k * 11 + c] = W[m];
    }
    __syncthreads();
    int row = (blockIdx.x * 256 + tid) >> 4;
    int c16 = tid & 15;
    if (row >= NN) return;
    size_t rb = (size_t)row * HID;
    float acc[NCLS];
#pragma unroll
    for (int c = 0; c < NCLS; ++c) acc[c] = 0.f;
#pragma unroll
    for (int j = 0; j < 8; ++j) {
        size_t idx = rb + c16 + 16 * j;
        float hv = __uint_as_float((unsigned)Ah[idx] << 16)
                 + __uint_as_float((unsigned)Am[idx] << 16)
                 + __uint_as_float((unsigned)Al[idx] << 16);
        const float* wr = &Ws[(c16 + 16 * j) * 11];
#pragma unroll
        for (int c = 0; c < NCLS; ++c) acc[c] += hv * wr[c];
    }
#pragma unroll
    for (int off = 8; off >= 1; off >>= 1) {
#pragma unroll
        for (int c = 0; c < NCLS; ++c) acc[c] += __shfl_xor(acc[c], off, 16);
    }
    if (c16 < NCLS) T2[(size_t)row * NCLS + c16] = acc[c16];
}

__global__ __launch_bounds__(256) void k_gather_out(const float* __restrict__ T2,
                                                    float* __restrict__ out,
                                                    const int* __restrict__ rowptr,
                                                    const int2* __restrict__ csr,
                                                    const float* __restrict__ dinv,
                                                    const float* __restrict__ bias) {
    int lane = threadIdx.x & 63;
    int node = (blockIdx.x * 256 + threadIdx.x) >> 6;
    if (node >= NN) return;
    int slot = lane >> 4, c = lane & 15;
    int beg = rowptr[node], end = rowptr[node + 1];
    float acc = 0.f;
    if (c < NCLS) {
        for (int i = beg + slot; i < end; i += 4) {
            int2 e = csr[i];
            acc += __int_as_float(e.y) * T2[(size_t)e.x * NCLS + c];
        }
    }
    acc += __shfl_xor(acc, 16, 64);
    acc += __shfl_xor(acc, 32, 64);
    if (slot == 0 && c < NCLS) {
        float sn = dinv[node];
        sn *= sn;
        out[node * NCLS + c] = acc + sn * T2[(size_t)node * NCLS + c] + bias[c];
    }
}

// ================= launch =================

extern "C" void kernel_launch(void* const* d_in, const int* in_sizes, int n_in,
                              void* d_out, int out_size, void* d_ws, size_t ws_size,
                              hipStream_t stream) {
    (void)in_sizes; (void)n_in; (void)out_size; (void)ws_size;
    const float* x       = (const float*)d_in[0];
    const int*   edge    = (const int*)d_in[1];   // [2, NE] int32
    const float* W_stack = (const float*)d_in[2];
    const float* b_stack = (const float*)d_in[3];
    const float* W_out   = (const float*)d_in[4];
    const float* b_out   = (const float*)d_in[5];
    float* out = (float*)d_out;

    char* ws = (char*)d_ws;
    float* Y      = (float*)ws;                       // T buffer, 25.6 MB
    char*  p      = ws + (size_t)NN * HID * sizeof(float);
    int2*  csr    = (int2*)p;              p += sizeof(int2) * NE;
    float* dinv   = (float*)p;             p += sizeof(float) * NN;
    int*   rowptr = (int*)p;               p += sizeof(int) * (NN + 1);
    int*   counts = (int*)p;               p += sizeof(int) * NN;    // reused as cursor
    int*   bsum   = (int*)p;               p += sizeof(int) * 256;
    p = (char*)(((size_t)p + 15) & ~(size_t)15);
    ushort* Ah  = (ushort*)p;  p += sizeof(ushort) * NN * HID;       // 12.8 MB each
    ushort* Am  = (ushort*)p;  p += sizeof(ushort) * NN * HID;
    ushort* Al  = (ushort*)p;  p += sizeof(ushort) * NN * HID;
    ushort* Wt3 = (ushort*)p;  p += sizeof(ushort) * 8 * 3 * HID * HID;

    const int NB_N  = (NN + 255) / 256;
    const int NB_E  = (NE + 255) / 256;
    const int NB_G  = (NN + 63) / 64;          // 782 MFMA-GEMM tiles
    const int NB_W  = (NN * 64 + 255) / 256;   // one wave per node
    const int NB_O  = (NN * 16 + 255) / 256;
    const int NB_SX = (NN * HID / 8 + 255) / 256;
    const int NB_SW = (8 * HID * HID + 255) / 256;

    // ---- CSR build (per call) ----
    hipMemsetAsync(counts, 0, sizeof(int) * NN, stream);
    k_count<<<NB_E, 256, 0, stream>>>(edge, counts);
    k_scan1<<<NB_N, 256, 0, stream>>>(counts, rowptr, bsum, dinv);
    k_scan2<<<1, 256, 0, stream>>>(bsum, NB_N);
    k_scan3<<<NB_N, 256, 0, stream>>>(rowptr, bsum);
    hipMemsetAsync(counts, 0, sizeof(int) * NN, stream);  // reuse as cursor
    k_fill<<<NB_E, 256, 0, stream>>>(edge, rowptr, counts, dinv, csr);

    // ---- one-time weight/input splits ----
    k_split_w<<<NB_SW, 256, 0, stream>>>(W_stack, Wt3);
    k_split_x<<<NB_SX, 256, 0, stream>>>(x, Ah, Am, Al);

    // ---- 8 hidden layers ----
    for (int l = 0; l < 8; ++l) {
        k_mfma_gemm<<<NB_G, 256, 0, stream>>>(Ah, Am, Al,
                                              Wt3 + (size_t)l * 3 * HID * HID, Y);
        k_gather_agg<<<NB_W, 256, 0, stream>>>(Y, Ah, Am, Al, rowptr, csr, dinv,
                                               b_stack + (size_t)l * HID);
    }

    // ---- output layer ----
    k_matmul_out<<<NB_O, 256, 0, stream>>>(Ah, Am, Al, W_out, Y);
    k_gather_out<<<NB_W, 256, 0, stream>>>(Y, out, rowptr, csr, dinv, b_out);
}

// Round 2
// 798.008 us; speedup vs baseline: 1.2520x; 1.2520x over previous
//
#include <hip/hip_runtime.h>
#include <math.h>

#define NN 50000
#define NE 600000
#define HID 128
#define NCLS 10

typedef __bf16 bf16x8 __attribute__((ext_vector_type(8)));
typedef float f32x16 __attribute__((ext_vector_type(16)));

// Exact 3-way bf16 split: f == hi + mid + lo (bit-truncation splits are exact;
// fp32 has 24 mantissa bits, 3x bf16 planes carry 8+8+8 = all of them).
__device__ __forceinline__ void split3(float f, ushort& h, ushort& m, ushort& l) {
    unsigned uh = __float_as_uint(f) & 0xffff0000u;
    float fm = f - __uint_as_float(uh);
    unsigned um = __float_as_uint(fm) & 0xffff0000u;
    float fl = fm - __uint_as_float(um);
    h = (ushort)(uh >> 16);
    m = (ushort)(um >> 16);
    l = (ushort)(__float_as_uint(fl) >> 16);
}

// ================= graph prep: CSR by destination =================

__global__ __launch_bounds__(256) void k_count(const int* __restrict__ edge,
                                               int* __restrict__ counts) {
    int e = blockIdx.x * 256 + threadIdx.x;
    if (e < NE) atomicAdd(&counts[edge[NE + e]], 1);
}

__device__ __forceinline__ int wave_incl_scan(int x, int lane) {
#pragma unroll
    for (int off = 1; off < 64; off <<= 1) {
        int y = __shfl_up(x, off, 64);
        if (lane >= off) x += y;
    }
    return x;
}

__global__ __launch_bounds__(256) void k_scan1(const int* __restrict__ counts,
                                               int* __restrict__ rowptr,
                                               int* __restrict__ bsum,
                                               float* __restrict__ dinv) {
    __shared__ int ws[4];
    int tid = threadIdx.x;
    int i = blockIdx.x * 256 + tid;
    int lane = tid & 63, wv = tid >> 6;
    int v = (i < NN) ? counts[i] : 0;
    if (i < NN) dinv[i] = rsqrtf((float)(v + 1));
    int x = wave_incl_scan(v, lane);
    if (lane == 63) ws[wv] = x;
    __syncthreads();
    int off = 0;
    for (int j = 0; j < wv; ++j) off += ws[j];
    if (i < NN) rowptr[i] = off + x - v;
    if (tid == 255) bsum[blockIdx.x] = off + x;
}

__global__ __launch_bounds__(256) void k_scan2(int* __restrict__ bsum, int n) {
    __shared__ int ws[4];
    int tid = threadIdx.x;
    int lane = tid & 63, wv = tid >> 6;
    int v = (tid < n) ? bsum[tid] : 0;
    int x = wave_incl_scan(v, lane);
    if (lane == 63) ws[wv] = x;
    __syncthreads();
    int off = 0;
    for (int j = 0; j < wv; ++j) off += ws[j];
    __syncthreads();
    if (tid < n) bsum[tid] = off + x - v;
}

__global__ __launch_bounds__(256) void k_scan3(int* __restrict__ rowptr,
                                               const int* __restrict__ bsum) {
    int i = blockIdx.x * 256 + threadIdx.x;
    if (i < NN) rowptr[i] += bsum[blockIdx.x];
    if (i == 0) rowptr[NN] = NE;
}

__global__ __launch_bounds__(256) void k_fill(const int* __restrict__ edge,
                                              const int* __restrict__ rowptr,
                                              int* __restrict__ cursor,
                                              const float* __restrict__ dinv,
                                              int2* __restrict__ csr) {
    int e = blockIdx.x * 256 + threadIdx.x;
    if (e >= NE) return;
    int s = edge[e], d = edge[NE + e];
    int p = rowptr[d] + atomicAdd(&cursor[d], 1);
    csr[p] = make_int2(s, __float_as_int(dinv[s] * dinv[d]));
}

// ================= one-time weight split =================
// W_stack [8][128 k][128 n] fp32 -> Wt3 [8][3 planes][128 n][128 k] bf16 (transposed)

__global__ __launch_bounds__(256) void k_split_w(const float* __restrict__ Wst,
                                                 ushort* __restrict__ Wt3) {
    int i = blockIdx.x * 256 + threadIdx.x;
    if (i >= 8 * HID * HID) return;
    int l = i >> 14;
    int k = (i >> 7) & 127;
    int n = i & 127;
    ushort h, m, lo;
    split3(Wst[i], h, m, lo);
    size_t base = (size_t)l * 3 * HID * HID + (size_t)n * HID + k;
    Wt3[base] = h;
    Wt3[base + HID * HID] = m;
    Wt3[base + 2 * HID * HID] = lo;
}

// ========== dense: H[NN,128] fp32 @ W[128,128] -> T fp32, via bf16 MFMA ==========
// fp32 A is split into 3 bf16 planes IN-REGISTER between global load and LDS
// write; 6 plane-products (hh, hm, mh, hl, mm, lh) reproduce fp32 accuracy.
// Tile 128x128, 4 waves (2x2), wave owns 64x64 = 2x2 fragments of 32x32.
// LDS rows stride 40 ushorts (80 B, 16B-aligned, odd granule) -> balanced banks.

__global__ __launch_bounds__(256) void k_mfma_gemm(const float* __restrict__ H,
                                                   const ushort* __restrict__ Wt,
                                                   float* __restrict__ T) {
    __shared__ ushort As[3][128][40];  // 30.7 KB
    __shared__ ushort Bs[3][128][40];  // 30.7 KB
    int tid = threadIdx.x;
    int lane = tid & 63, w = tid >> 6;
    int wy = w >> 1, wx = w & 1;
    int l31 = lane & 31, lh = lane >> 5;
    int rowbase = blockIdx.x * 128;

    // A staging: 2 threads per row, each covers 16 consecutive fp32 (64 B)
    int arow = tid >> 1;
    int kh = (tid & 1) * 16;
    int garow = rowbase + arow;
    if (garow >= NN) garow = NN - 1;  // clamp; stores predicated below
    size_t aoff = (size_t)garow * HID;

    f32x16 acc[2][2] = {};

    for (int k0 = 0; k0 < HID; k0 += 32) {
        // ---- issue global loads ----
        const float4* asrc = (const float4*)(H + aoff + k0 + kh);
        float4 af0 = asrc[0], af1 = asrc[1], af2 = asrc[2], af3 = asrc[3];
        uint4 rb[6];
#pragma unroll
        for (int c = 0; c < 6; ++c) {
            int chunk = c * 256 + tid;
            int p = chunk >> 9;
            int rem = chunk & 511;
            int col = rem >> 2;
            int q = rem & 3;
            rb[c] = *(const uint4*)(Wt + p * (HID * HID) + col * HID + k0 + q * 8);
        }
        // ---- split A in-register ----
        float av[16] = {af0.x, af0.y, af0.z, af0.w, af1.x, af1.y, af1.z, af1.w,
                        af2.x, af2.y, af2.z, af2.w, af3.x, af3.y, af3.z, af3.w};
        union { ushort u[16]; uint4 v[2]; } ph, pm, pl;
#pragma unroll
        for (int q = 0; q < 16; ++q) split3(av[q], ph.u[q], pm.u[q], pl.u[q]);

        __syncthreads();  // previous iter's LDS reads done
        *(uint4*)&As[0][arow][kh] = ph.v[0];
        *(uint4*)&As[0][arow][kh + 8] = ph.v[1];
        *(uint4*)&As[1][arow][kh] = pm.v[0];
        *(uint4*)&As[1][arow][kh + 8] = pm.v[1];
        *(uint4*)&As[2][arow][kh] = pl.v[0];
        *(uint4*)&As[2][arow][kh + 8] = pl.v[1];
#pragma unroll
        for (int c = 0; c < 6; ++c) {
            int chunk = c * 256 + tid;
            int p = chunk >> 9;
            int rem = chunk & 511;
            int col = rem >> 2;
            int q = rem & 3;
            *(uint4*)&Bs[p][col][q * 8] = rb[c];
        }
        __syncthreads();

        // ---- compute ----
#pragma unroll
        for (int ks = 0; ks < 32; ks += 16) {
            int kk = ks + lh * 8;
            bf16x8 a[3][2], b[3][2];
#pragma unroll
            for (int p = 0; p < 3; ++p)
#pragma unroll
                for (int h = 0; h < 2; ++h) {
                    a[p][h] = *(const bf16x8*)&As[p][wy * 64 + h * 32 + l31][kk];
                    b[p][h] = *(const bf16x8*)&Bs[p][wx * 64 + h * 32 + l31][kk];
                }
            // 6 plane products, each over the 2x2 fragment grid (independent accs)
#pragma unroll
            for (int h = 0; h < 2; ++h)
#pragma unroll
                for (int c = 0; c < 2; ++c)
                    acc[h][c] = __builtin_amdgcn_mfma_f32_32x32x16_bf16(a[0][h], b[0][c], acc[h][c], 0, 0, 0);
#pragma unroll
            for (int h = 0; h < 2; ++h)
#pragma unroll
                for (int c = 0; c < 2; ++c)
                    acc[h][c] = __builtin_amdgcn_mfma_f32_32x32x16_bf16(a[0][h], b[1][c], acc[h][c], 0, 0, 0);
#pragma unroll
            for (int h = 0; h < 2; ++h)
#pragma unroll
                for (int c = 0; c < 2; ++c)
                    acc[h][c] = __builtin_amdgcn_mfma_f32_32x32x16_bf16(a[1][h], b[0][c], acc[h][c], 0, 0, 0);
#pragma unroll
            for (int h = 0; h < 2; ++h)
#pragma unroll
                for (int c = 0; c < 2; ++c)
                    acc[h][c] = __builtin_amdgcn_mfma_f32_32x32x16_bf16(a[0][h], b[2][c], acc[h][c], 0, 0, 0);
#pragma unroll
            for (int h = 0; h < 2; ++h)
#pragma unroll
                for (int c = 0; c < 2; ++c)
                    acc[h][c] = __builtin_amdgcn_mfma_f32_32x32x16_bf16(a[1][h], b[1][c], acc[h][c], 0, 0, 0);
#pragma unroll
            for (int h = 0; h < 2; ++h)
#pragma unroll
                for (int c = 0; c < 2; ++c)
                    acc[h][c] = __builtin_amdgcn_mfma_f32_32x32x16_bf16(a[2][h], b[0][c], acc[h][c], 0, 0, 0);
        }
    }
    // C/D layout: col = lane&31, row = (reg&3) + 8*(reg>>2) + 4*(lane>>5)
#pragma unroll
    for (int h = 0; h < 2; ++h)
#pragma unroll
        for (int c = 0; c < 2; ++c)
#pragma unroll
            for (int reg = 0; reg < 16; ++reg) {
                int r = (reg & 3) + 8 * (reg >> 2) + 4 * lh;
                int gr = rowbase + wy * 64 + h * 32 + r;
                if (gr < NN)
                    T[(size_t)gr * HID + wx * 64 + c * 32 + l31] = acc[h][c][reg];
            }
}

// ============ sparse by gather: one wave per node, pipelined, fused epilogue ============

__global__ __launch_bounds__(256) void k_gather_agg(const float* __restrict__ T,
                                                    float* __restrict__ Hout,
                                                    const int* __restrict__ rowptr,
                                                    const int2* __restrict__ csr,
                                                    const float* __restrict__ dinv,
                                                    const float* __restrict__ bias) {
    int lane = threadIdx.x & 63;
    int node = (blockIdx.x * 256 + threadIdx.x) >> 6;
    if (node >= NN) return;
    int slot = lane >> 4, c16 = lane & 15;

    int beg = rowptr[node], end = rowptr[node + 1];
    float4 acc0 = {0.f, 0.f, 0.f, 0.f}, acc1 = {0.f, 0.f, 0.f, 0.f};
    const int2 zed = make_int2(0, 0);  // norm bits 0 -> weight 0

    int i = beg + slot;
    int2 e0 = (i < end) ? csr[i] : zed;
    int2 e1 = (i + 4 < end) ? csr[i + 4] : zed;
    for (; i < end; i += 8) {
        int2 p0 = (i + 8 < end) ? csr[i + 8] : zed;
        int2 p1 = (i + 12 < end) ? csr[i + 12] : zed;
        const float4* s0 = (const float4*)(T + (size_t)e0.x * HID) + c16 * 2;
        const float4* s1 = (const float4*)(T + (size_t)e1.x * HID) + c16 * 2;
        float4 u0 = s0[0], u1 = s0[1];
        float4 v0 = s1[0], v1 = s1[1];
        float w0 = __int_as_float(e0.y);
        float w1 = __int_as_float(e1.y);
        acc0.x += w0 * u0.x; acc0.y += w0 * u0.y; acc0.z += w0 * u0.z; acc0.w += w0 * u0.w;
        acc1.x += w0 * u1.x; acc1.y += w0 * u1.y; acc1.z += w0 * u1.z; acc1.w += w0 * u1.w;
        acc0.x += w1 * v0.x; acc0.y += w1 * v0.y; acc0.z += w1 * v0.z; acc0.w += w1 * v0.w;
        acc1.x += w1 * v1.x; acc1.y += w1 * v1.y; acc1.z += w1 * v1.z; acc1.w += w1 * v1.w;
        e0 = p0; e1 = p1;
    }
    acc0.x += __shfl_xor(acc0.x, 16, 64); acc0.y += __shfl_xor(acc0.y, 16, 64);
    acc0.z += __shfl_xor(acc0.z, 16, 64); acc0.w += __shfl_xor(acc0.w, 16, 64);
    acc1.x += __shfl_xor(acc1.x, 16, 64); acc1.y += __shfl_xor(acc1.y, 16, 64);
    acc1.z += __shfl_xor(acc1.z, 16, 64); acc1.w += __shfl_xor(acc1.w, 16, 64);
    acc0.x += __shfl_xor(acc0.x, 32, 64); acc0.y += __shfl_xor(acc0.y, 32, 64);
    acc0.z += __shfl_xor(acc0.z, 32, 64); acc0.w += __shfl_xor(acc0.w, 32, 64);
    acc1.x += __shfl_xor(acc1.x, 32, 64); acc1.y += __shfl_xor(acc1.y, 32, 64);
    acc1.z += __shfl_xor(acc1.z, 32, 64); acc1.w += __shfl_xor(acc1.w, 32, 64);

    if (slot == 0) {
        float sn = dinv[node];
        sn *= sn;
        const float4* trow = (const float4*)(T + (size_t)node * HID) + c16 * 2;
        float4 t0 = trow[0], t1 = trow[1];
        const float4* b4 = (const float4*)bias + c16 * 2;
        float4 b0 = b4[0], b1 = b4[1];
        float4 r0, r1;
        r0.x = acc0.x + sn * t0.x + b0.x; r0.y = acc0.y + sn * t0.y + b0.y;
        r0.z = acc0.z + sn * t0.z + b0.z; r0.w = acc0.w + sn * t0.w + b0.w;
        r1.x = acc1.x + sn * t1.x + b1.x; r1.y = acc1.y + sn * t1.y + b1.y;
        r1.z = acc1.z + sn * t1.z + b1.z; r1.w = acc1.w + sn * t1.w + b1.w;
        r0.x = r0.x > 0.f ? r0.x : expm1f(r0.x);
        r0.y = r0.y > 0.f ? r0.y : expm1f(r0.y);
        r0.z = r0.z > 0.f ? r0.z : expm1f(r0.z);
        r0.w = r0.w > 0.f ? r0.w : expm1f(r0.w);
        r1.x = r1.x > 0.f ? r1.x : expm1f(r1.x);
        r1.y = r1.y > 0.f ? r1.y : expm1f(r1.y);
        r1.z = r1.z > 0.f ? r1.z : expm1f(r1.z);
        r1.w = r1.w > 0.f ? r1.w : expm1f(r1.w);
        float4* dst = (float4*)(Hout + (size_t)node * HID) + c16 * 2;
        dst[0] = r0;
        dst[1] = r1;
    }
}

// ================= output layer (128 -> 10) =================

__global__ __launch_bounds__(256) void k_matmul_out(const float* __restrict__ H,
                                                    const float* __restrict__ W,
                                                    float* __restrict__ T2) {
    __shared__ float Ws[128 * 11];
    int tid = threadIdx.x;
    for (int m = tid; m < HID * NCLS; m += 256) {
        int k = m / NCLS, c = m - k * NCLS;
        Ws[k * 11 + c] = W[m];
    }
    __syncthreads();
    int row = (blockIdx.x * 256 + tid) >> 4;
    int c16 = tid & 15;
    if (row >= NN) return;
    const float* h = H + (size_t)row * HID;
    float acc[NCLS];
#pragma unroll
    for (int c = 0; c < NCLS; ++c) acc[c] = 0.f;
#pragma unroll
    for (int j = 0; j < 8; ++j) {
        float hv = h[c16 + 16 * j];
        const float* wr = &Ws[(c16 + 16 * j) * 11];
#pragma unroll
        for (int c = 0; c < NCLS; ++c) acc[c] += hv * wr[c];
    }
#pragma unroll
    for (int off = 8; off >= 1; off >>= 1) {
#pragma unroll
        for (int c = 0; c < NCLS; ++c) acc[c] += __shfl_xor(acc[c], off, 16);
    }
    if (c16 < NCLS) T2[(size_t)row * NCLS + c16] = acc[c16];
}

__global__ __launch_bounds__(256) void k_gather_out(const float* __restrict__ T2,
                                                    float* __restrict__ out,
                                                    const int* __restrict__ rowptr,
                                                    const int2* __restrict__ csr,
                                                    const float* __restrict__ dinv,
                                                    const float* __restrict__ bias) {
    int lane = threadIdx.x & 63;
    int node = (blockIdx.x * 256 + threadIdx.x) >> 6;
    if (node >= NN) return;
    int slot = lane >> 4, c = lane & 15;
    int beg = rowptr[node], end = rowptr[node + 1];
    float acc = 0.f;
    if (c < NCLS) {
        for (int i = beg + slot; i < end; i += 4) {
            int2 e = csr[i];
            acc += __int_as_float(e.y) * T2[(size_t)e.x * NCLS + c];
        }
    }
    acc += __shfl_xor(acc, 16, 64);
    acc += __shfl_xor(acc, 32, 64);
    if (slot == 0 && c < NCLS) {
        float sn = dinv[node];
        sn *= sn;
        out[node * NCLS + c] = acc + sn * T2[(size_t)node * NCLS + c] + bias[c];
    }
}

// ================= launch =================

extern "C" void kernel_launch(void* const* d_in, const int* in_sizes, int n_in,
                              void* d_out, int out_size, void* d_ws, size_t ws_size,
                              hipStream_t stream) {
    (void)in_sizes; (void)n_in; (void)out_size; (void)ws_size;
    const float* x       = (const float*)d_in[0];
    const int*   edge    = (const int*)d_in[1];   // [2, NE] int32
    const float* W_stack = (const float*)d_in[2];
    const float* b_stack = (const float*)d_in[3];
    const float* W_out   = (const float*)d_in[4];
    const float* b_out   = (const float*)d_in[5];
    float* out = (float*)d_out;

    char* ws = (char*)d_ws;
    const size_t bigbuf = (size_t)NN * HID * sizeof(float);  // 25.6 MB
    float* X      = (float*)ws;
    float* Y      = (float*)(ws + bigbuf);
    char*  p      = ws + 2 * bigbuf;
    int2*  csr    = (int2*)p;              p += sizeof(int2) * NE;
    float* dinv   = (float*)p;             p += sizeof(float) * NN;
    int*   rowptr = (int*)p;               p += sizeof(int) * (NN + 1);
    int*   counts = (int*)p;               p += sizeof(int) * NN;    // reused as cursor
    int*   bsum   = (int*)p;               p += sizeof(int) * 256;
    p = (char*)(((size_t)p + 15) & ~(size_t)15);
    ushort* Wt3 = (ushort*)p;  p += sizeof(ushort) * 8 * 3 * HID * HID;  // 786 KB

    const int NB_N  = (NN + 255) / 256;
    const int NB_E  = (NE + 255) / 256;
    const int NB_G  = (NN + 127) / 128;        // 391 MFMA-GEMM tiles
    const int NB_W  = (NN * 64 + 255) / 256;   // one wave per node
    const int NB_O  = (NN * 16 + 255) / 256;
    const int NB_SW = (8 * HID * HID + 255) / 256;

    // ---- CSR build (per call) ----
    hipMemsetAsync(counts, 0, sizeof(int) * NN, stream);
    k_count<<<NB_E, 256, 0, stream>>>(edge, counts);
    k_scan1<<<NB_N, 256, 0, stream>>>(counts, rowptr, bsum, dinv);
    k_scan2<<<1, 256, 0, stream>>>(bsum, NB_N);
    k_scan3<<<NB_N, 256, 0, stream>>>(rowptr, bsum);
    hipMemsetAsync(counts, 0, sizeof(int) * NN, stream);  // reuse as cursor
    k_fill<<<NB_E, 256, 0, stream>>>(edge, rowptr, counts, dinv, csr);

    // ---- one-time weight split ----
    k_split_w<<<NB_SW, 256, 0, stream>>>(W_stack, Wt3);

    // ---- 8 hidden layers ----
    const float* Hin = x;
    for (int l = 0; l < 8; ++l) {
        k_mfma_gemm<<<NB_G, 256, 0, stream>>>(Hin, Wt3 + (size_t)l * 3 * HID * HID, Y);
        k_gather_agg<<<NB_W, 256, 0, stream>>>(Y, X, rowptr, csr, dinv,
                                               b_stack + (size_t)l * HID);
        Hin = X;
    }

    // ---- output layer ----
    k_matmul_out<<<NB_O, 256, 0, stream>>>(X, W_out, Y);
    k_gather_out<<<NB_W, 256, 0, stream>>>(Y, out, rowptr, csr, dinv, b_out);
}

// Round 3
// 788.805 us; speedup vs baseline: 1.2666x; 1.0117x over previous
//
#include <hip/hip_runtime.h>
#include <math.h>

#define NN 50000
#define NE 600000
#define HID 128
#define NCLS 10

typedef __bf16 bf16x8 __attribute__((ext_vector_type(8)));
typedef float f32x16 __attribute__((ext_vector_type(16)));

// Exact 3-way bf16 split: f == hi + mid + lo (bit-truncation splits are exact;
// fp32 has 24 mantissa bits, 3x bf16 planes carry 8+8+8 = all of them).
__device__ __forceinline__ void split3(float f, ushort& h, ushort& m, ushort& l) {
    unsigned uh = __float_as_uint(f) & 0xffff0000u;
    float fm = f - __uint_as_float(uh);
    unsigned um = __float_as_uint(fm) & 0xffff0000u;
    float fl = fm - __uint_as_float(um);
    h = (ushort)(uh >> 16);
    m = (ushort)(um >> 16);
    l = (ushort)(__float_as_uint(fl) >> 16);
}

// ================= graph prep: CSR by destination =================

__global__ __launch_bounds__(256) void k_count(const int* __restrict__ edge,
                                               int* __restrict__ counts) {
    int e = blockIdx.x * 256 + threadIdx.x;
    if (e < NE) atomicAdd(&counts[edge[NE + e]], 1);
}

__device__ __forceinline__ int wave_incl_scan(int x, int lane) {
#pragma unroll
    for (int off = 1; off < 64; off <<= 1) {
        int y = __shfl_up(x, off, 64);
        if (lane >= off) x += y;
    }
    return x;
}

__global__ __launch_bounds__(256) void k_scan1(const int* __restrict__ counts,
                                               int* __restrict__ rowptr,
                                               int* __restrict__ bsum,
                                               float* __restrict__ dinv) {
    __shared__ int ws[4];
    int tid = threadIdx.x;
    int i = blockIdx.x * 256 + tid;
    int lane = tid & 63, wv = tid >> 6;
    int v = (i < NN) ? counts[i] : 0;
    if (i < NN) dinv[i] = rsqrtf((float)(v + 1));
    int x = wave_incl_scan(v, lane);
    if (lane == 63) ws[wv] = x;
    __syncthreads();
    int off = 0;
    for (int j = 0; j < wv; ++j) off += ws[j];
    if (i < NN) rowptr[i] = off + x - v;
    if (tid == 255) bsum[blockIdx.x] = off + x;
}

__global__ __launch_bounds__(256) void k_scan2(int* __restrict__ bsum, int n) {
    __shared__ int ws[4];
    int tid = threadIdx.x;
    int lane = tid & 63, wv = tid >> 6;
    int v = (tid < n) ? bsum[tid] : 0;
    int x = wave_incl_scan(v, lane);
    if (lane == 63) ws[wv] = x;
    __syncthreads();
    int off = 0;
    for (int j = 0; j < wv; ++j) off += ws[j];
    __syncthreads();
    if (tid < n) bsum[tid] = off + x - v;
}

__global__ __launch_bounds__(256) void k_scan3(int* __restrict__ rowptr,
                                               const int* __restrict__ bsum) {
    int i = blockIdx.x * 256 + threadIdx.x;
    if (i < NN) rowptr[i] += bsum[blockIdx.x];
    if (i == 0) rowptr[NN] = NE;
}

__global__ __launch_bounds__(256) void k_fill(const int* __restrict__ edge,
                                              const int* __restrict__ rowptr,
                                              int* __restrict__ cursor,
                                              const float* __restrict__ dinv,
                                              int2* __restrict__ csr) {
    int e = blockIdx.x * 256 + threadIdx.x;
    if (e >= NE) return;
    int s = edge[e], d = edge[NE + e];
    int p = rowptr[d] + atomicAdd(&cursor[d], 1);
    csr[p] = make_int2(s, __float_as_int(dinv[s] * dinv[d]));
}

// ================= one-time weight split =================
// W_stack [8][128 k][128 n] fp32 -> Wt3 [8][3 planes][128 n][128 k] bf16 (transposed)

__global__ __launch_bounds__(256) void k_split_w(const float* __restrict__ Wst,
                                                 ushort* __restrict__ Wt3) {
    int i = blockIdx.x * 256 + threadIdx.x;
    if (i >= 8 * HID * HID) return;
    int l = i >> 14;
    int k = (i >> 7) & 127;
    int n = i & 127;
    ushort h, m, lo;
    split3(Wst[i], h, m, lo);
    size_t base = (size_t)l * 3 * HID * HID + (size_t)n * HID + k;
    Wt3[base] = h;
    Wt3[base + HID * HID] = m;
    Wt3[base + 2 * HID * HID] = lo;
}

// ========== dense: H[NN,128] fp32 @ W[128,128] -> T fp32, via bf16 MFMA ==========
// fp32 A is split into 3 bf16 planes IN-REGISTER between global load and LDS
// write; 6 plane-products (hh, hm, mh, hl, mm, lh) reproduce fp32 accuracy.
// Tile 128x128, 4 waves (2x2), wave owns 64x64 = 2x2 fragments of 32x32.
// LDS rows stride 40 ushorts (80 B, 16B-aligned, odd granule) -> balanced banks.

__global__ __launch_bounds__(256) void k_mfma_gemm(const float* __restrict__ H,
                                                   const ushort* __restrict__ Wt,
                                                   float* __restrict__ T) {
    __shared__ ushort As[3][128][40];  // 30.7 KB
    __shared__ ushort Bs[3][128][40];  // 30.7 KB
    int tid = threadIdx.x;
    int lane = tid & 63, w = tid >> 6;
    int wy = w >> 1, wx = w & 1;
    int l31 = lane & 31, lh = lane >> 5;
    int rowbase = blockIdx.x * 128;

    // A staging: 2 threads per row, each covers 16 consecutive fp32 (64 B)
    int arow = tid >> 1;
    int kh = (tid & 1) * 16;
    int garow = rowbase + arow;
    if (garow >= NN) garow = NN - 1;  // clamp; stores predicated below
    size_t aoff = (size_t)garow * HID;

    f32x16 acc[2][2] = {};

    for (int k0 = 0; k0 < HID; k0 += 32) {
        // ---- issue global loads ----
        const float4* asrc = (const float4*)(H + aoff + k0 + kh);
        float4 af0 = asrc[0], af1 = asrc[1], af2 = asrc[2], af3 = asrc[3];
        uint4 rb[6];
#pragma unroll
        for (int c = 0; c < 6; ++c) {
            int chunk = c * 256 + tid;
            int p = chunk >> 9;
            int rem = chunk & 511;
            int col = rem >> 2;
            int q = rem & 3;
            rb[c] = *(const uint4*)(Wt + p * (HID * HID) + col * HID + k0 + q * 8);
        }
        // ---- split A in-register ----
        float av[16] = {af0.x, af0.y, af0.z, af0.w, af1.x, af1.y, af1.z, af1.w,
                        af2.x, af2.y, af2.z, af2.w, af3.x, af3.y, af3.z, af3.w};
        union { ushort u[16]; uint4 v[2]; } ph, pm, pl;
#pragma unroll
        for (int q = 0; q < 16; ++q) split3(av[q], ph.u[q], pm.u[q], pl.u[q]);

        __syncthreads();  // previous iter's LDS reads done
        *(uint4*)&As[0][arow][kh] = ph.v[0];
        *(uint4*)&As[0][arow][kh + 8] = ph.v[1];
        *(uint4*)&As[1][arow][kh] = pm.v[0];
        *(uint4*)&As[1][arow][kh + 8] = pm.v[1];
        *(uint4*)&As[2][arow][kh] = pl.v[0];
        *(uint4*)&As[2][arow][kh + 8] = pl.v[1];
#pragma unroll
        for (int c = 0; c < 6; ++c) {
            int chunk = c * 256 + tid;
            int p = chunk >> 9;
            int rem = chunk & 511;
            int col = rem >> 2;
            int q = rem & 3;
            *(uint4*)&Bs[p][col][q * 8] = rb[c];
        }
        __syncthreads();

        // ---- compute ----
#pragma unroll
        for (int ks = 0; ks < 32; ks += 16) {
            int kk = ks + lh * 8;
            bf16x8 a[3][2], b[3][2];
#pragma unroll
            for (int p = 0; p < 3; ++p)
#pragma unroll
                for (int h = 0; h < 2; ++h) {
                    a[p][h] = *(const bf16x8*)&As[p][wy * 64 + h * 32 + l31][kk];
                    b[p][h] = *(const bf16x8*)&Bs[p][wx * 64 + h * 32 + l31][kk];
                }
            // 6 plane products, each over the 2x2 fragment grid (independent accs)
#pragma unroll
            for (int h = 0; h < 2; ++h)
#pragma unroll
                for (int c = 0; c < 2; ++c)
                    acc[h][c] = __builtin_amdgcn_mfma_f32_32x32x16_bf16(a[0][h], b[0][c], acc[h][c], 0, 0, 0);
#pragma unroll
            for (int h = 0; h < 2; ++h)
#pragma unroll
                for (int c = 0; c < 2; ++c)
                    acc[h][c] = __builtin_amdgcn_mfma_f32_32x32x16_bf16(a[0][h], b[1][c], acc[h][c], 0, 0, 0);
#pragma unroll
            for (int h = 0; h < 2; ++h)
#pragma unroll
                for (int c = 0; c < 2; ++c)
                    acc[h][c] = __builtin_amdgcn_mfma_f32_32x32x16_bf16(a[1][h], b[0][c], acc[h][c], 0, 0, 0);
#pragma unroll
            for (int h = 0; h < 2; ++h)
#pragma unroll
                for (int c = 0; c < 2; ++c)
                    acc[h][c] = __builtin_amdgcn_mfma_f32_32x32x16_bf16(a[0][h], b[2][c], acc[h][c], 0, 0, 0);
#pragma unroll
            for (int h = 0; h < 2; ++h)
#pragma unroll
                for (int c = 0; c < 2; ++c)
                    acc[h][c] = __builtin_amdgcn_mfma_f32_32x32x16_bf16(a[1][h], b[1][c], acc[h][c], 0, 0, 0);
#pragma unroll
            for (int h = 0; h < 2; ++h)
#pragma unroll
                for (int c = 0; c < 2; ++c)
                    acc[h][c] = __builtin_amdgcn_mfma_f32_32x32x16_bf16(a[2][h], b[0][c], acc[h][c], 0, 0, 0);
        }
    }
    // C/D layout: col = lane&31, row = (reg&3) + 8*(reg>>2) + 4*(lane>>5)
#pragma unroll
    for (int h = 0; h < 2; ++h)
#pragma unroll
        for (int c = 0; c < 2; ++c)
#pragma unroll
            for (int reg = 0; reg < 16; ++reg) {
                int r = (reg & 3) + 8 * (reg >> 2) + 4 * lh;
                int gr = rowbase + wy * 64 + h * 32 + r;
                if (gr < NN)
                    T[(size_t)gr * HID + wx * 64 + c * 32 + l31] = acc[h][c][reg];
            }
}

// ============ sparse by gather: 32 lanes per node, no cross-lane reduction ============
// Each lane owns 4 columns (float4 at l31*4). 2 nodes per wave; edge loop
// unrolled x4 with csr prefetch -> 4 row loads in flight per node-group.
// Self-row/bias/dinv loads hoisted above the loop. Fused bias+ELU epilogue.

__global__ __launch_bounds__(256) void k_gather_agg(const float* __restrict__ T,
                                                    float* __restrict__ Hout,
                                                    const int* __restrict__ rowptr,
                                                    const int2* __restrict__ csr,
                                                    const float* __restrict__ dinv,
                                                    const float* __restrict__ bias) {
    int node = (blockIdx.x * 256 + threadIdx.x) >> 5;
    if (node >= NN) return;
    int l31 = threadIdx.x & 31;

    int beg = rowptr[node], end = rowptr[node + 1];
    // hoisted loads: overlap the whole edge loop
    float sn = dinv[node];
    float4 bv = ((const float4*)bias)[l31];
    float4 tv = ((const float4*)(T + (size_t)node * HID))[l31];

    float4 acc = {0.f, 0.f, 0.f, 0.f};
    const int2 zed = make_int2(0, 0);  // norm bits 0 -> weight 0 (reads row 0, harmless)

    int i = beg;
    int2 e0 = (i < end) ? csr[i] : zed;
    int2 e1 = (i + 1 < end) ? csr[i + 1] : zed;
    int2 e2 = (i + 2 < end) ? csr[i + 2] : zed;
    int2 e3 = (i + 3 < end) ? csr[i + 3] : zed;
    for (; i < end; i += 4) {
        float4 u0 = ((const float4*)(T + (size_t)e0.x * HID))[l31];
        float4 u1 = ((const float4*)(T + (size_t)e1.x * HID))[l31];
        float4 u2 = ((const float4*)(T + (size_t)e2.x * HID))[l31];
        float4 u3 = ((const float4*)(T + (size_t)e3.x * HID))[l31];
        float w0 = __int_as_float(e0.y), w1 = __int_as_float(e1.y);
        float w2 = __int_as_float(e2.y), w3 = __int_as_float(e3.y);
        e0 = (i + 4 < end) ? csr[i + 4] : zed;
        e1 = (i + 5 < end) ? csr[i + 5] : zed;
        e2 = (i + 6 < end) ? csr[i + 6] : zed;
        e3 = (i + 7 < end) ? csr[i + 7] : zed;
        acc.x += w0 * u0.x; acc.y += w0 * u0.y; acc.z += w0 * u0.z; acc.w += w0 * u0.w;
        acc.x += w1 * u1.x; acc.y += w1 * u1.y; acc.z += w1 * u1.z; acc.w += w1 * u1.w;
        acc.x += w2 * u2.x; acc.y += w2 * u2.y; acc.z += w2 * u2.z; acc.w += w2 * u2.w;
        acc.x += w3 * u3.x; acc.y += w3 * u3.y; acc.z += w3 * u3.z; acc.w += w3 * u3.w;
    }

    sn *= sn;
    float4 r;
    r.x = acc.x + sn * tv.x + bv.x;
    r.y = acc.y + sn * tv.y + bv.y;
    r.z = acc.z + sn * tv.z + bv.z;
    r.w = acc.w + sn * tv.w + bv.w;
    r.x = r.x > 0.f ? r.x : expm1f(r.x);
    r.y = r.y > 0.f ? r.y : expm1f(r.y);
    r.z = r.z > 0.f ? r.z : expm1f(r.z);
    r.w = r.w > 0.f ? r.w : expm1f(r.w);
    ((float4*)(Hout + (size_t)node * HID))[l31] = r;
}

// ================= output layer (128 -> 10) =================

__global__ __launch_bounds__(256) void k_matmul_out(const float* __restrict__ H,
                                                    const float* __restrict__ W,
                                                    float* __restrict__ T2) {
    __shared__ float Ws[128 * 11];
    int tid = threadIdx.x;
    for (int m = tid; m < HID * NCLS; m += 256) {
        int k = m / NCLS, c = m - k * NCLS;
        Ws[k * 11 + c] = W[m];
    }
    __syncthreads();
    int row = (blockIdx.x * 256 + tid) >> 4;
    int c16 = tid & 15;
    if (row >= NN) return;
    const float* h = H + (size_t)row * HID;
    float acc[NCLS];
#pragma unroll
    for (int c = 0; c < NCLS; ++c) acc[c] = 0.f;
#pragma unroll
    for (int j = 0; j < 8; ++j) {
        float hv = h[c16 + 16 * j];
        const float* wr = &Ws[(c16 + 16 * j) * 11];
#pragma unroll
        for (int c = 0; c < NCLS; ++c) acc[c] += hv * wr[c];
    }
#pragma unroll
    for (int off = 8; off >= 1; off >>= 1) {
#pragma unroll
        for (int c = 0; c < NCLS; ++c) acc[c] += __shfl_xor(acc[c], off, 16);
    }
    if (c16 < NCLS) T2[(size_t)row * NCLS + c16] = acc[c16];
}

__global__ __launch_bounds__(256) void k_gather_out(const float* __restrict__ T2,
                                                    float* __restrict__ out,
                                                    const int* __restrict__ rowptr,
                                                    const int2* __restrict__ csr,
                                                    const float* __restrict__ dinv,
                                                    const float* __restrict__ bias) {
    int lane = threadIdx.x & 63;
    int node = (blockIdx.x * 256 + threadIdx.x) >> 6;
    if (node >= NN) return;
    int slot = lane >> 4, c = lane & 15;
    int beg = rowptr[node], end = rowptr[node + 1];
    float acc = 0.f;
    if (c < NCLS) {
        for (int i = beg + slot; i < end; i += 4) {
            int2 e = csr[i];
            acc += __int_as_float(e.y) * T2[(size_t)e.x * NCLS + c];
        }
    }
    acc += __shfl_xor(acc, 16, 64);
    acc += __shfl_xor(acc, 32, 64);
    if (slot == 0 && c < NCLS) {
        float sn = dinv[node];
        sn *= sn;
        out[node * NCLS + c] = acc + sn * T2[(size_t)node * NCLS + c] + bias[c];
    }
}

// ================= launch =================

extern "C" void kernel_launch(void* const* d_in, const int* in_sizes, int n_in,
                              void* d_out, int out_size, void* d_ws, size_t ws_size,
                              hipStream_t stream) {
    (void)in_sizes; (void)n_in; (void)out_size; (void)ws_size;
    const float* x       = (const float*)d_in[0];
    const int*   edge    = (const int*)d_in[1];   // [2, NE] int32
    const float* W_stack = (const float*)d_in[2];
    const float* b_stack = (const float*)d_in[3];
    const float* W_out   = (const float*)d_in[4];
    const float* b_out   = (const float*)d_in[5];
    float* out = (float*)d_out;

    char* ws = (char*)d_ws;
    const size_t bigbuf = (size_t)NN * HID * sizeof(float);  // 25.6 MB
    float* X      = (float*)ws;
    float* Y      = (float*)(ws + bigbuf);
    char*  p      = ws + 2 * bigbuf;
    int2*  csr    = (int2*)p;              p += sizeof(int2) * NE;
    float* dinv   = (float*)p;             p += sizeof(float) * NN;
    int*   rowptr = (int*)p;               p += sizeof(int) * (NN + 1);
    int*   counts = (int*)p;               p += sizeof(int) * NN;    // reused as cursor
    int*   bsum   = (int*)p;               p += sizeof(int) * 256;
    p = (char*)(((size_t)p + 15) & ~(size_t)15);
    ushort* Wt3 = (ushort*)p;  p += sizeof(ushort) * 8 * 3 * HID * HID;  // 786 KB

    const int NB_N  = (NN + 255) / 256;
    const int NB_E  = (NE + 255) / 256;
    const int NB_G  = (NN + 127) / 128;        // 391 MFMA-GEMM tiles
    const int NB_A  = (NN * 32 + 255) / 256;   // 32 lanes per node
    const int NB_W  = (NN * 64 + 255) / 256;   // one wave per node (out layer)
    const int NB_O  = (NN * 16 + 255) / 256;
    const int NB_SW = (8 * HID * HID + 255) / 256;

    // ---- CSR build (per call) ----
    hipMemsetAsync(counts, 0, sizeof(int) * NN, stream);
    k_count<<<NB_E, 256, 0, stream>>>(edge, counts);
    k_scan1<<<NB_N, 256, 0, stream>>>(counts, rowptr, bsum, dinv);
    k_scan2<<<1, 256, 0, stream>>>(bsum, NB_N);
    k_scan3<<<NB_N, 256, 0, stream>>>(rowptr, bsum);
    hipMemsetAsync(counts, 0, sizeof(int) * NN, stream);  // reuse as cursor
    k_fill<<<NB_E, 256, 0, stream>>>(edge, rowptr, counts, dinv, csr);

    // ---- one-time weight split ----
    k_split_w<<<NB_SW, 256, 0, stream>>>(W_stack, Wt3);

    // ---- 8 hidden layers ----
    const float* Hin = x;
    for (int l = 0; l < 8; ++l) {
        k_mfma_gemm<<<NB_G, 256, 0, stream>>>(Hin, Wt3 + (size_t)l * 3 * HID * HID, Y);
        k_gather_agg<<<NB_A, 256, 0, stream>>>(Y, X, rowptr, csr, dinv,
                                               b_stack + (size_t)l * HID);
        Hin = X;
    }

    // ---- output layer ----
    k_matmul_out<<<NB_O, 256, 0, stream>>>(X, W_out, Y);
    k_gather_out<<<NB_W, 256, 0, stream>>>(Y, out, rowptr, csr, dinv, b_out);
}